// Round 3
// baseline (3048.269 us; speedup 1.0000x reference)
//
#include <hip/hip_runtime.h>
#include <hip/hip_bf16.h>
#include <stdint.h>

#define D 256

typedef __attribute__((ext_vector_type(8))) short bf16x8;
typedef __attribute__((ext_vector_type(4))) float f32x4;
typedef __attribute__((ext_vector_type(4))) unsigned int u32x4;

#define GLOBAL_AS __attribute__((address_space(1)))
#define LDS_AS __attribute__((address_space(3)))

__device__ __forceinline__ unsigned short f2bf(float f) {
  union { float f; unsigned int u; } c; c.f = f;
  unsigned int r = (c.u + 0x7fffu + ((c.u >> 16) & 1u)) >> 16;
  return (unsigned short)r;
}
__device__ __forceinline__ float bf2f(unsigned short h) {
  union { unsigned int u; float f; } c; c.u = ((unsigned int)h) << 16;
  return c.f;
}

// ---------------- prep: x fp32 -> bf16 ----------------
__global__ void convert_x_kernel(const float* __restrict__ x,
                                 unsigned short* __restrict__ xb, int n4) {
  int i = blockIdx.x * blockDim.x + threadIdx.x;
  if (i >= n4) return;
  float4 v = reinterpret_cast<const float4*>(x)[i];
  ushort4 o;
  o.x = f2bf(v.x); o.y = f2bf(v.y); o.z = f2bf(v.z); o.w = f2bf(v.w);
  reinterpret_cast<ushort4*>(xb)[i] = o;
}

// ---------------- prep: Wt[r][h][d] = W_r[d][h] (bf16), r==R -> W_self ----------------
__global__ void transpose_w_kernel(const float* __restrict__ Wrel,
                                   const float* __restrict__ Wself,
                                   unsigned short* __restrict__ Wt, int R) {
  __shared__ unsigned short tile[64][65];
  int r = blockIdx.z;
  const float* src = (r == R) ? Wself : (Wrel + (size_t)r * D * D);
  int d0 = blockIdx.x * 64, h0 = blockIdx.y * 64;
  for (int i = threadIdx.x; i < 64 * 64; i += blockDim.x) {
    int row = i >> 6, col = i & 63;  // row: d, col: h
    tile[row][col] = f2bf(src[(size_t)(d0 + row) * D + h0 + col]);
  }
  __syncthreads();
  for (int i = threadIdx.x; i < 64 * 64; i += blockDim.x) {
    int row = i >> 6, col = i & 63;  // row: h, col: d
    Wt[(size_t)r * D * D + (size_t)(h0 + row) * D + d0 + col] = tile[col][row];
  }
}

// ---------------- MFMA GEMM: C = A(M,256) @ Bt(n,256)^T ----------------
// XB=1: A is bf16 (global_load_lds staging). XB=0: A is fp32 (reg-stage + cvt).
// MODE 0: C -> Cbf (bf16), width ldc, LDS-staged epilogue
// MODE 1: C -> Cf (fp32) + bias, ldc = 256, direct stores
template <int MODE, int XB>
__global__ __launch_bounds__(256) void gemm_kernel(
    const unsigned short* __restrict__ Abf,
    const float* __restrict__ Af,
    const unsigned short* __restrict__ Bt,
    unsigned short* __restrict__ Cbf,
    float* __restrict__ Cf,
    const float* __restrict__ bias, int M, int ldc) {
  __shared__ unsigned short smem[128 * 128];  // 32KB; As=[0,8192), Bs=[8192,16384)
  unsigned short* As = smem;
  unsigned short* Bs = smem + 8192;

  const int tid = threadIdx.x;
  const int lane = tid & 63;
  const int wid = tid >> 6;
  const int wm = wid >> 1, wn = wid & 1;
  const int m0 = blockIdx.x * 128;
  const int n0 = blockIdx.y * 128;

  f32x4 acc[4][4] = {};

  for (int k0 = 0; k0 < 256; k0 += 64) {
    __syncthreads();  // previous iter's LDS reads done
    // B tile: 128x64 bf16 = 16 chunks of 1KB, async direct-to-LDS
    for (int i = 0; i < 4; ++i) {
      int chunk = i * 4 + wid;               // 0..15
      int row = chunk * 8 + (lane >> 3);     // 0..127
      int col = (lane & 7) * 8;              // 0..56
      const unsigned short* gb = Bt + (size_t)(n0 + row) * 256 + k0 + col;
      __builtin_amdgcn_global_load_lds((GLOBAL_AS void*)(void*)gb,
                                       (LDS_AS void*)(Bs + chunk * 512), 16, 0, 0);
    }
    if (XB) {
      for (int i = 0; i < 4; ++i) {
        int chunk = i * 4 + wid;
        int row = chunk * 8 + (lane >> 3);
        int col = (lane & 7) * 8;
        int ar = m0 + row; if (ar > M - 1) ar = M - 1;
        const unsigned short* ga = Abf + (size_t)ar * 256 + k0 + col;
        __builtin_amdgcn_global_load_lds((GLOBAL_AS void*)(void*)ga,
                                         (LDS_AS void*)(As + chunk * 512), 16, 0, 0);
      }
    } else {
      // reg-staged fp32 -> bf16: 128x64 tile, 8 float4 per thread
      for (int i = 0; i < 8; ++i) {
        int idx = i * 256 + tid;     // 0..2047
        int row = idx >> 4;          // 0..127
        int c4 = idx & 15;           // 0..15 (x4 floats)
        int ar = m0 + row; if (ar > M - 1) ar = M - 1;
        float4 v = *reinterpret_cast<const float4*>(Af + (size_t)ar * 256 + k0 + c4 * 4);
        ushort4 o;
        o.x = f2bf(v.x); o.y = f2bf(v.y); o.z = f2bf(v.z); o.w = f2bf(v.w);
        *reinterpret_cast<ushort4*>(&As[row * 64 + c4 * 4]) = o;
      }
    }
    __syncthreads();  // drains vmcnt + lgkmcnt -> LDS ready
    for (int kk = 0; kk < 2; ++kk) {
      bf16x8 af[4], bfr[4];
      int kof = kk * 32 + (lane >> 4) * 8;
      for (int mi = 0; mi < 4; ++mi)
        af[mi] = *(const bf16x8*)&As[(wm * 64 + mi * 16 + (lane & 15)) * 64 + kof];
      for (int ni = 0; ni < 4; ++ni)
        bfr[ni] = *(const bf16x8*)&Bs[(wn * 64 + ni * 16 + (lane & 15)) * 64 + kof];
      for (int mi = 0; mi < 4; ++mi)
        for (int ni = 0; ni < 4; ++ni)
          acc[mi][ni] = __builtin_amdgcn_mfma_f32_16x16x32_bf16(
              af[mi], bfr[ni], acc[mi][ni], 0, 0, 0);
    }
  }

  if (MODE == 1) {
    for (int mi = 0; mi < 4; ++mi)
      for (int ni = 0; ni < 4; ++ni) {
        int col = n0 + wn * 64 + ni * 16 + (lane & 15);
        int rbase = m0 + wm * 64 + mi * 16 + (lane >> 4) * 4;
        float b = bias[col];
        for (int j = 0; j < 4; ++j) {
          int row = rbase + j;
          if (row < M) Cf[(size_t)row * 256 + col] = acc[mi][ni][j] + b;
        }
      }
  } else {
    __syncthreads();  // all LDS reads of K-loop done before overwrite
    for (int mi = 0; mi < 4; ++mi)
      for (int ni = 0; ni < 4; ++ni) {
        int colt = wn * 64 + ni * 16 + (lane & 15);
        int rbt = wm * 64 + mi * 16 + (lane >> 4) * 4;
        for (int j = 0; j < 4; ++j)
          smem[(rbt + j) * 128 + colt] = f2bf(acc[mi][ni][j]);
      }
    __syncthreads();
    for (int i = 0; i < 8; ++i) {
      int c = i * 256 + tid;        // 0..2047 chunks of 16B
      int row = c >> 4;             // 0..127
      int cole = (c & 15) * 8;      // 0..120
      int grow = m0 + row;
      if (grow < M)
        *(u32x4*)&Cbf[(size_t)grow * ldc + n0 + cole] =
            *(const u32x4*)&smem[row * 128 + cole];
    }
  }
}

// ---------------- edge scatter for relation batch [relLo, relLo+RB) ----------------
__global__ void scatter_kernel(const int* __restrict__ ei, const int* __restrict__ et,
                               const unsigned short* __restrict__ xw,
                               float* __restrict__ out, int E, int M, int RB, int relLo) {
  int w = blockIdx.x * (blockDim.x >> 6) + (threadIdx.x >> 6);
  int lane = threadIdx.x & 63;
  int nw = gridDim.x * (blockDim.x >> 6);
  for (int e = w; e < E; e += nw) {
    int rel = et[e];
    if (rel < relLo || rel >= relLo + RB) continue;
    int src = ei[e];
    int dst = ei[E + e];
    // defensive clamps: any encoding surprise -> wrong numbers, not a fault
    src = min(max(src, 0), M - 1);
    dst = min(max(dst, 0), M - 1);
    ushort4 v = *((const ushort4*)(xw + ((size_t)src * RB + (rel - relLo)) * 256) + lane);
    float* o = out + (size_t)dst * 256 + lane * 4;
    atomicAdd(o + 0, bf2f(v.x));
    atomicAdd(o + 1, bf2f(v.y));
    atomicAdd(o + 2, bf2f(v.z));
    atomicAdd(o + 3, bf2f(v.w));
  }
}

// ---------------- relu in place ----------------
__global__ void relu_kernel(float* __restrict__ out, int n4) {
  int i = blockIdx.x * blockDim.x + threadIdx.x;
  if (i >= n4) return;
  float4 v = reinterpret_cast<float4*>(out)[i];
  v.x = fmaxf(v.x, 0.f); v.y = fmaxf(v.y, 0.f);
  v.z = fmaxf(v.z, 0.f); v.w = fmaxf(v.w, 0.f);
  reinterpret_cast<float4*>(out)[i] = v;
}

// ======== ws-free fallback tier (correctness only; used only if ws too small) ========
// out[n,:] = bias + x[n,:] @ W_self   (one wave per node, direct stores)
__global__ void fb_self_kernel(const float* __restrict__ x,
                               const float* __restrict__ Wself,
                               const float* __restrict__ bias,
                               float* __restrict__ out, int M) {
  int w = blockIdx.x * (blockDim.x >> 6) + (threadIdx.x >> 6);
  int lane = threadIdx.x & 63;
  int nw = gridDim.x * (blockDim.x >> 6);
  for (int n = w; n < M; n += nw) {
    float a0 = 0, a1 = 0, a2 = 0, a3 = 0;
    const float* xr = x + (size_t)n * 256;
    for (int d = 0; d < 256; ++d) {
      float xv = xr[d];
      float4 wv = *reinterpret_cast<const float4*>(Wself + (size_t)d * 256 + lane * 4);
      a0 = fmaf(xv, wv.x, a0); a1 = fmaf(xv, wv.y, a1);
      a2 = fmaf(xv, wv.z, a2); a3 = fmaf(xv, wv.w, a3);
    }
    float4 b = *reinterpret_cast<const float4*>(bias + lane * 4);
    float4 o = {a0 + b.x, a1 + b.y, a2 + b.z, a3 + b.w};
    *reinterpret_cast<float4*>(out + (size_t)n * 256 + lane * 4) = o;
  }
}

// out[dst,:] += x[src,:] @ W_rel[rel]  (one wave per edge, atomics)
__global__ void fb_edge_kernel(const int* __restrict__ ei, const int* __restrict__ et,
                               const float* __restrict__ x,
                               const float* __restrict__ Wrel,
                               float* __restrict__ out, int E, int M, int R) {
  int w = blockIdx.x * (blockDim.x >> 6) + (threadIdx.x >> 6);
  int lane = threadIdx.x & 63;
  int nw = gridDim.x * (blockDim.x >> 6);
  for (int e = w; e < E; e += nw) {
    int src = min(max(ei[e], 0), M - 1);
    int dst = min(max(ei[E + e], 0), M - 1);
    int rel = min(max(et[e], 0), R - 1);
    const float* xr = x + (size_t)src * 256;
    const float* W = Wrel + (size_t)rel * 256 * 256;
    float a0 = 0, a1 = 0, a2 = 0, a3 = 0;
    for (int d = 0; d < 256; ++d) {
      float xv = xr[d];
      float4 wv = *reinterpret_cast<const float4*>(W + (size_t)d * 256 + lane * 4);
      a0 = fmaf(xv, wv.x, a0); a1 = fmaf(xv, wv.y, a1);
      a2 = fmaf(xv, wv.z, a2); a3 = fmaf(xv, wv.w, a3);
    }
    float* o = out + (size_t)dst * 256 + lane * 4;
    atomicAdd(o + 0, a0);
    atomicAdd(o + 1, a1);
    atomicAdd(o + 2, a2);
    atomicAdd(o + 3, a3);
  }
}

extern "C" void kernel_launch(void* const* d_in, const int* in_sizes, int n_in,
                              void* d_out, int out_size, void* d_ws, size_t ws_size,
                              hipStream_t stream) {
  const float* x = (const float*)d_in[0];
  const int* ei = (const int*)d_in[1];
  const int* et = (const int*)d_in[2];
  const float* Wrel = (const float*)d_in[3];
  const float* Wself = (const float*)d_in[4];
  const float* bias = (const float*)d_in[5];
  float* out = (float*)d_out;

  const int M = in_sizes[0] / D;        // nodes
  const int E = in_sizes[1] / 2;        // edges
  const int R = in_sizes[3] / (D * D);  // relations

  const int MB = (M + 127) / 128;
  const int n4 = M * D / 4;

  // Workspace plan (bf16 elements): [Wt (R+1)*D*D][xb? M*D][xw M*RB*D]
  // Chosen purely from ws_size -> identical work every call (graph-safe).
  const size_t wtElems = (size_t)(R + 1) * D * D;
  const size_t xbElems = (size_t)M * D;
  const size_t yElems = (size_t)M * D;  // per relation
  const size_t wsElems = ws_size / 2;

  int use_xb = 0, RB = 0;
  for (int rb = R; rb >= 1; rb >>= 1) {
    if (wtElems + xbElems + 512 + yElems * (size_t)rb <= wsElems) {
      use_xb = 1; RB = rb; break;
    }
  }
  if (!use_xb) {
    for (int rb = R; rb >= 1; rb >>= 1) {
      if (wtElems + 512 + yElems * (size_t)rb <= wsElems) { RB = rb; break; }
    }
  }

  if (RB == 0) {
    // ---- ws-free fallback: correct for ANY ws_size (touches d_ws never) ----
    fb_self_kernel<<<2048, 256, 0, stream>>>(x, Wself, bias, out, M);
    fb_edge_kernel<<<2048, 256, 0, stream>>>(ei, et, x, Wrel, out, E, M, R);
    relu_kernel<<<(n4 + 255) / 256, 256, 0, stream>>>(out, n4);
    return;
  }

  unsigned short* Wt = (unsigned short*)d_ws;
  size_t off = wtElems + (use_xb ? xbElems : 0);
  off = (off + 255) & ~(size_t)255;
  unsigned short* xb = Wt + wtElems;
  unsigned short* xw = Wt + off;
  const int nb = R / RB;

  transpose_w_kernel<<<dim3(4, 4, R + 1), 256, 0, stream>>>(Wrel, Wself, Wt, R);
  if (use_xb)
    convert_x_kernel<<<(n4 + 255) / 256, 256, 0, stream>>>(x, xb, n4);

  // out = x @ W_self + bias
  if (use_xb)
    gemm_kernel<1, 1><<<dim3(MB, 2), 256, 0, stream>>>(
        xb, nullptr, Wt + (size_t)R * D * D, nullptr, out, bias, M, 256);
  else
    gemm_kernel<1, 0><<<dim3(MB, 2), 256, 0, stream>>>(
        nullptr, x, Wt + (size_t)R * D * D, nullptr, out, bias, M, 256);

  // per relation-batch: xw = x @ W_r^T for r in batch, then scatter edges
  for (int b = 0; b < nb; ++b) {
    const unsigned short* BtB = Wt + (size_t)b * RB * D * D;
    if (use_xb)
      gemm_kernel<0, 1><<<dim3(MB, RB * 2), 256, 0, stream>>>(
          xb, nullptr, BtB, xw, nullptr, nullptr, M, RB * 256);
    else
      gemm_kernel<0, 0><<<dim3(MB, RB * 2), 256, 0, stream>>>(
          nullptr, x, BtB, xw, nullptr, nullptr, M, RB * 256);
    scatter_kernel<<<2048, 256, 0, stream>>>(ei, et, xw, out, E, M, RB, b * RB);
  }

  relu_kernel<<<(n4 + 255) / 256, 256, 0, stream>>>(out, n4);
}

// Round 4
// 676.225 us; speedup vs baseline: 4.5078x; 4.5078x over previous
//
#include <hip/hip_runtime.h>
#include <hip/hip_bf16.h>
#include <stdint.h>

#define D 256

typedef __attribute__((ext_vector_type(8))) short bf16x8;
typedef __attribute__((ext_vector_type(4))) float f32x4;
typedef __attribute__((ext_vector_type(4))) unsigned int u32x4;

#define GLOBAL_AS __attribute__((address_space(1)))
#define LDS_AS __attribute__((address_space(3)))

__device__ __forceinline__ unsigned short f2bf(float f) {
  union { float f; unsigned int u; } c; c.f = f;
  unsigned int r = (c.u + 0x7fffu + ((c.u >> 16) & 1u)) >> 16;
  return (unsigned short)r;
}
__device__ __forceinline__ float bf2f(unsigned short h) {
  union { unsigned int u; float f; } c; c.u = ((unsigned int)h) << 16;
  return c.f;
}

// ---------------- prep: x fp32 -> bf16 ----------------
__global__ void convert_x_kernel(const float* __restrict__ x,
                                 unsigned short* __restrict__ xb, int n4) {
  int i = blockIdx.x * blockDim.x + threadIdx.x;
  if (i >= n4) return;
  float4 v = reinterpret_cast<const float4*>(x)[i];
  ushort4 o;
  o.x = f2bf(v.x); o.y = f2bf(v.y); o.z = f2bf(v.z); o.w = f2bf(v.w);
  reinterpret_cast<ushort4*>(xb)[i] = o;
}

// ---------------- prep: Wt[r][h][d] = W_r[d][h] (bf16), r==R -> W_self ----------------
__global__ void transpose_w_kernel(const float* __restrict__ Wrel,
                                   const float* __restrict__ Wself,
                                   unsigned short* __restrict__ Wt, int R) {
  __shared__ unsigned short tile[64][65];
  int r = blockIdx.z;
  const float* src = (r == R) ? Wself : (Wrel + (size_t)r * D * D);
  int d0 = blockIdx.x * 64, h0 = blockIdx.y * 64;
  for (int i = threadIdx.x; i < 64 * 64; i += blockDim.x) {
    int row = i >> 6, col = i & 63;  // row: d, col: h
    tile[row][col] = f2bf(src[(size_t)(d0 + row) * D + h0 + col]);
  }
  __syncthreads();
  for (int i = threadIdx.x; i < 64 * 64; i += blockDim.x) {
    int row = i >> 6, col = i & 63;  // row: h, col: d
    Wt[(size_t)r * D * D + (size_t)(h0 + row) * D + d0 + col] = tile[col][row];
  }
}

// ---------------- MFMA GEMM: C = A(M,256) @ Bt(n,256)^T ----------------
// XB=1: A is bf16 (global_load_lds staging). XB=0: A is fp32 (reg-stage + cvt).
// MODE 0: C -> Cbf (bf16), width ldc, LDS-staged epilogue
// MODE 1: C -> Cf (fp32) + bias, ldc = 256, direct stores
template <int MODE, int XB>
__global__ __launch_bounds__(256) void gemm_kernel(
    const unsigned short* __restrict__ Abf,
    const float* __restrict__ Af,
    const unsigned short* __restrict__ Bt,
    unsigned short* __restrict__ Cbf,
    float* __restrict__ Cf,
    const float* __restrict__ bias, int M, int ldc) {
  __shared__ unsigned short smem[128 * 128];  // 32KB; As=[0,8192), Bs=[8192,16384)
  unsigned short* As = smem;
  unsigned short* Bs = smem + 8192;

  const int tid = threadIdx.x;
  const int lane = tid & 63;
  const int wid = tid >> 6;
  const int wm = wid >> 1, wn = wid & 1;
  const int m0 = blockIdx.x * 128;
  const int n0 = blockIdx.y * 128;

  f32x4 acc[4][4] = {};

  for (int k0 = 0; k0 < 256; k0 += 64) {
    __syncthreads();  // previous iter's LDS reads done
    for (int i = 0; i < 4; ++i) {
      int chunk = i * 4 + wid;               // 0..15
      int row = chunk * 8 + (lane >> 3);     // 0..127
      int col = (lane & 7) * 8;              // 0..56
      const unsigned short* gb = Bt + (size_t)(n0 + row) * 256 + k0 + col;
      __builtin_amdgcn_global_load_lds((GLOBAL_AS void*)(void*)gb,
                                       (LDS_AS void*)(Bs + chunk * 512), 16, 0, 0);
    }
    if (XB) {
      for (int i = 0; i < 4; ++i) {
        int chunk = i * 4 + wid;
        int row = chunk * 8 + (lane >> 3);
        int col = (lane & 7) * 8;
        int ar = m0 + row; if (ar > M - 1) ar = M - 1;
        const unsigned short* ga = Abf + (size_t)ar * 256 + k0 + col;
        __builtin_amdgcn_global_load_lds((GLOBAL_AS void*)(void*)ga,
                                         (LDS_AS void*)(As + chunk * 512), 16, 0, 0);
      }
    } else {
      for (int i = 0; i < 8; ++i) {
        int idx = i * 256 + tid;     // 0..2047
        int row = idx >> 4;          // 0..127
        int c4 = idx & 15;           // 0..15 (x4 floats)
        int ar = m0 + row; if (ar > M - 1) ar = M - 1;
        float4 v = *reinterpret_cast<const float4*>(Af + (size_t)ar * 256 + k0 + c4 * 4);
        ushort4 o;
        o.x = f2bf(v.x); o.y = f2bf(v.y); o.z = f2bf(v.z); o.w = f2bf(v.w);
        *reinterpret_cast<ushort4*>(&As[row * 64 + c4 * 4]) = o;
      }
    }
    __syncthreads();  // drains vmcnt + lgkmcnt -> LDS ready
    for (int kk = 0; kk < 2; ++kk) {
      bf16x8 af[4], bfr[4];
      int kof = kk * 32 + (lane >> 4) * 8;
      for (int mi = 0; mi < 4; ++mi)
        af[mi] = *(const bf16x8*)&As[(wm * 64 + mi * 16 + (lane & 15)) * 64 + kof];
      for (int ni = 0; ni < 4; ++ni)
        bfr[ni] = *(const bf16x8*)&Bs[(wn * 64 + ni * 16 + (lane & 15)) * 64 + kof];
      for (int mi = 0; mi < 4; ++mi)
        for (int ni = 0; ni < 4; ++ni)
          acc[mi][ni] = __builtin_amdgcn_mfma_f32_16x16x32_bf16(
              af[mi], bfr[ni], acc[mi][ni], 0, 0, 0);
    }
  }

  if (MODE == 1) {
    for (int mi = 0; mi < 4; ++mi)
      for (int ni = 0; ni < 4; ++ni) {
        int col = n0 + wn * 64 + ni * 16 + (lane & 15);
        int rbase = m0 + wm * 64 + mi * 16 + (lane >> 4) * 4;
        float b = bias[col];
        for (int j = 0; j < 4; ++j) {
          int row = rbase + j;
          if (row < M) Cf[(size_t)row * 256 + col] = acc[mi][ni][j] + b;
        }
      }
  } else {
    __syncthreads();  // all LDS reads of K-loop done before overwrite
    for (int mi = 0; mi < 4; ++mi)
      for (int ni = 0; ni < 4; ++ni) {
        int colt = wn * 64 + ni * 16 + (lane & 15);
        int rbt = wm * 64 + mi * 16 + (lane >> 4) * 4;
        for (int j = 0; j < 4; ++j)
          smem[(rbt + j) * 128 + colt] = f2bf(acc[mi][ni][j]);
      }
    __syncthreads();
    for (int i = 0; i < 8; ++i) {
      int c = i * 256 + tid;        // 0..2047 chunks of 16B
      int row = c >> 4;             // 0..127
      int cole = (c & 15) * 8;      // 0..120
      int grow = m0 + row;
      if (grow < M)
        *(u32x4*)&Cbf[(size_t)grow * ldc + n0 + cole] =
            *(const u32x4*)&smem[row * 128 + cole];
    }
  }
}

// ================= CSR build (histogram + 2-level exclusive scan + fill) =================
__global__ void hist_kernel(const int* __restrict__ ei, int* __restrict__ counts,
                            int E, int M) {
  for (int i = blockIdx.x * blockDim.x + threadIdx.x; i < E;
       i += gridDim.x * blockDim.x) {
    int dst = min(max(ei[E + i], 0), M - 1);
    atomicAdd(&counts[dst], 1);
  }
}

__global__ void scan1_kernel(const int* __restrict__ counts, int* __restrict__ bsum,
                             int M) {
  __shared__ int red[256];
  int i = blockIdx.x * 256 + threadIdx.x;
  red[threadIdx.x] = (i < M) ? counts[i] : 0;
  __syncthreads();
  for (int s = 128; s > 0; s >>= 1) {
    if (threadIdx.x < s) red[threadIdx.x] += red[threadIdx.x + s];
    __syncthreads();
  }
  if (threadIdx.x == 0) bsum[blockIdx.x] = red[0];
}

__global__ void scan2_kernel(int* __restrict__ bsum, int NB) {  // exclusive, NB<=1024
  __shared__ int sh[1024];
  int t = threadIdx.x;
  int v = (t < NB) ? bsum[t] : 0;
  sh[t] = v;
  __syncthreads();
  for (int off = 1; off < 1024; off <<= 1) {
    int u = (t >= off) ? sh[t - off] : 0;
    __syncthreads();
    sh[t] += u;
    __syncthreads();
  }
  if (t < NB) bsum[t] = sh[t] - v;
}

__global__ void scan3_kernel(const int* __restrict__ counts, const int* __restrict__ bsum,
                             int* __restrict__ offs, int M) {
  __shared__ int sh[256];
  int b = blockIdx.x, t = threadIdx.x;
  int i = b * 256 + t;
  int v = (i < M) ? counts[i] : 0;
  sh[t] = v;
  __syncthreads();
  for (int off = 1; off < 256; off <<= 1) {
    int u = (t >= off) ? sh[t - off] : 0;
    __syncthreads();
    sh[t] += u;
    __syncthreads();
  }
  int excl = sh[t] - v + bsum[b];
  if (i < M) offs[i] = excl;
  if (i == M - 1) offs[M] = excl + v;
}

__global__ void fill_kernel(const int* __restrict__ ei, const int* __restrict__ et,
                            const int* __restrict__ offs, int* __restrict__ cursor,
                            int* __restrict__ ev, int E, int M, int R) {
  for (int i = blockIdx.x * blockDim.x + threadIdx.x; i < E;
       i += gridDim.x * blockDim.x) {
    int dst = min(max(ei[E + i], 0), M - 1);
    int src = min(max(ei[i], 0), M - 1);
    int rel = min(max(et[i], 0), R - 1);
    int p = atomicAdd(&cursor[dst], 1);
    ev[offs[dst] + p] = src * R + rel;
  }
}

// ---------------- gather: out[n] += sum over CSR edges of xw[src,rel] ----------------
// one wave per destination node; no atomics (each node owned by exactly one wave)
__global__ void gather_kernel(const int* __restrict__ offs, const int* __restrict__ ev,
                              const unsigned short* __restrict__ xw,
                              float* __restrict__ out, int M, int R, int RB, int relLo) {
  int w = blockIdx.x * (blockDim.x >> 6) + (threadIdx.x >> 6);
  int lane = threadIdx.x & 63;
  if (w >= M) return;
  int beg = offs[w], end = offs[w + 1];
  float a0 = 0, a1 = 0, a2 = 0, a3 = 0;
  bool any = false;
  for (int s = beg; s < end; ++s) {
    int v = ev[s];
    int src = v / R;
    int rel = v - src * R;
    if (rel < relLo || rel >= relLo + RB) continue;
    any = true;
    ushort4 t = *((const ushort4*)(xw + ((size_t)src * RB + (rel - relLo)) * 256) + lane);
    a0 += bf2f(t.x); a1 += bf2f(t.y); a2 += bf2f(t.z); a3 += bf2f(t.w);
  }
  if (any) {
    float4* o = (float4*)(out + (size_t)w * 256) + lane;
    float4 cur = *o;
    cur.x += a0; cur.y += a1; cur.z += a2; cur.w += a3;
    *o = cur;
  }
}

// ---------------- relu in place ----------------
__global__ void relu_kernel(float* __restrict__ out, int n4) {
  int i = blockIdx.x * blockDim.x + threadIdx.x;
  if (i >= n4) return;
  float4 v = reinterpret_cast<float4*>(out)[i];
  v.x = fmaxf(v.x, 0.f); v.y = fmaxf(v.y, 0.f);
  v.z = fmaxf(v.z, 0.f); v.w = fmaxf(v.w, 0.f);
  reinterpret_cast<float4*>(out)[i] = v;
}

// ======== ws-free fallback tier (correctness only; used only if ws too small) ========
__global__ void fb_self_kernel(const float* __restrict__ x,
                               const float* __restrict__ Wself,
                               const float* __restrict__ bias,
                               float* __restrict__ out, int M) {
  int w = blockIdx.x * (blockDim.x >> 6) + (threadIdx.x >> 6);
  int lane = threadIdx.x & 63;
  int nw = gridDim.x * (blockDim.x >> 6);
  for (int n = w; n < M; n += nw) {
    float a0 = 0, a1 = 0, a2 = 0, a3 = 0;
    const float* xr = x + (size_t)n * 256;
    for (int d = 0; d < 256; ++d) {
      float xv = xr[d];
      float4 wv = *reinterpret_cast<const float4*>(Wself + (size_t)d * 256 + lane * 4);
      a0 = fmaf(xv, wv.x, a0); a1 = fmaf(xv, wv.y, a1);
      a2 = fmaf(xv, wv.z, a2); a3 = fmaf(xv, wv.w, a3);
    }
    float4 b = *reinterpret_cast<const float4*>(bias + lane * 4);
    float4 o = {a0 + b.x, a1 + b.y, a2 + b.z, a3 + b.w};
    *reinterpret_cast<float4*>(out + (size_t)n * 256 + lane * 4) = o;
  }
}

__global__ void fb_edge_kernel(const int* __restrict__ ei, const int* __restrict__ et,
                               const float* __restrict__ x,
                               const float* __restrict__ Wrel,
                               float* __restrict__ out, int E, int M, int R) {
  int w = blockIdx.x * (blockDim.x >> 6) + (threadIdx.x >> 6);
  int lane = threadIdx.x & 63;
  int nw = gridDim.x * (blockDim.x >> 6);
  for (int e = w; e < E; e += nw) {
    int src = min(max(ei[e], 0), M - 1);
    int dst = min(max(ei[E + e], 0), M - 1);
    int rel = min(max(et[e], 0), R - 1);
    const float* xr = x + (size_t)src * 256;
    const float* W = Wrel + (size_t)rel * 256 * 256;
    float a0 = 0, a1 = 0, a2 = 0, a3 = 0;
    for (int d = 0; d < 256; ++d) {
      float xv = xr[d];
      float4 wv = *reinterpret_cast<const float4*>(W + (size_t)d * 256 + lane * 4);
      a0 = fmaf(xv, wv.x, a0); a1 = fmaf(xv, wv.y, a1);
      a2 = fmaf(xv, wv.z, a2); a3 = fmaf(xv, wv.w, a3);
    }
    float* o = out + (size_t)dst * 256 + lane * 4;
    atomicAdd(o + 0, a0);
    atomicAdd(o + 1, a1);
    atomicAdd(o + 2, a2);
    atomicAdd(o + 3, a3);
  }
}

extern "C" void kernel_launch(void* const* d_in, const int* in_sizes, int n_in,
                              void* d_out, int out_size, void* d_ws, size_t ws_size,
                              hipStream_t stream) {
  const float* x = (const float*)d_in[0];
  const int* ei = (const int*)d_in[1];
  const int* et = (const int*)d_in[2];
  const float* Wrel = (const float*)d_in[3];
  const float* Wself = (const float*)d_in[4];
  const float* bias = (const float*)d_in[5];
  float* out = (float*)d_out;

  const int M = in_sizes[0] / D;        // nodes
  const int E = in_sizes[1] / 2;        // edges
  const int R = in_sizes[3] / (D * D);  // relations

  const int MB = (M + 127) / 128;
  const int n4 = M * D / 4;
  const int NB2 = (M + 255) / 256;      // scan partial blocks (<=1024 required)

  // ---- ws layout: [int CSR arrays][bf16: Wt | xb? | xw] ----
  const size_t intCount = (size_t)M + (M + 1) + NB2 + M + E;
  const size_t intBytes = intCount * 4;
  const size_t wtElems = (size_t)(R + 1) * D * D;
  const size_t xbElems = (size_t)M * D;
  const size_t yElems = (size_t)M * D;  // per relation
  const size_t bfAvail = (ws_size > intBytes + 128) ? (ws_size - intBytes - 128) / 2 : 0;

  int use_xb = 0, RB = 0;
  for (int rb = R; rb >= 1; rb >>= 1) {
    if (wtElems + xbElems + 512 + yElems * (size_t)rb <= bfAvail) {
      use_xb = 1; RB = rb; break;
    }
  }
  if (!use_xb) {
    for (int rb = R; rb >= 1; rb >>= 1) {
      if (wtElems + 512 + yElems * (size_t)rb <= bfAvail) { RB = rb; break; }
    }
  }

  if (RB == 0 || NB2 > 1024) {
    // ---- ws-free fallback: correct for ANY ws_size (never touches d_ws) ----
    fb_self_kernel<<<2048, 256, 0, stream>>>(x, Wself, bias, out, M);
    fb_edge_kernel<<<2048, 256, 0, stream>>>(ei, et, x, Wrel, out, E, M, R);
    relu_kernel<<<(n4 + 255) / 256, 256, 0, stream>>>(out, n4);
    return;
  }

  int* counts = (int*)d_ws;        // M
  int* offs = counts + M;          // M+1
  int* bsum = offs + M + 1;        // NB2
  int* cursor = bsum + NB2;        // M
  int* ev = cursor + M;            // E
  uintptr_t bfp = (uintptr_t)(ev + E);
  bfp = (bfp + 127) & ~(uintptr_t)127;
  unsigned short* Wt = (unsigned short*)bfp;
  unsigned short* xb = Wt + wtElems;
  size_t off = wtElems + (use_xb ? xbElems : 0);
  off = (off + 255) & ~(size_t)255;
  unsigned short* xw = Wt + off;
  const int nb = R / RB;

  // ---- CSR build ----
  hipMemsetAsync(counts, 0, ((size_t)3 * M + 1 + NB2) * 4, stream);  // counts..cursor
  hist_kernel<<<1024, 256, 0, stream>>>(ei, counts, E, M);
  scan1_kernel<<<NB2, 256, 0, stream>>>(counts, bsum, M);
  scan2_kernel<<<1, 1024, 0, stream>>>(bsum, NB2);
  scan3_kernel<<<NB2, 256, 0, stream>>>(counts, bsum, offs, M);
  fill_kernel<<<1024, 256, 0, stream>>>(ei, et, offs, cursor, ev, E, M, R);

  // ---- dense path ----
  transpose_w_kernel<<<dim3(4, 4, R + 1), 256, 0, stream>>>(Wrel, Wself, Wt, R);
  if (use_xb)
    convert_x_kernel<<<(n4 + 255) / 256, 256, 0, stream>>>(x, xb, n4);

  if (use_xb)
    gemm_kernel<1, 1><<<dim3(MB, 2), 256, 0, stream>>>(
        xb, nullptr, Wt + (size_t)R * D * D, nullptr, out, bias, M, 256);
  else
    gemm_kernel<1, 0><<<dim3(MB, 2), 256, 0, stream>>>(
        nullptr, x, Wt + (size_t)R * D * D, nullptr, out, bias, M, 256);

  for (int b = 0; b < nb; ++b) {
    const unsigned short* BtB = Wt + (size_t)b * RB * D * D;
    if (use_xb)
      gemm_kernel<0, 1><<<dim3(MB, RB * 2), 256, 0, stream>>>(
          xb, nullptr, BtB, xw, nullptr, nullptr, M, RB * 256);
    else
      gemm_kernel<0, 0><<<dim3(MB, RB * 2), 256, 0, stream>>>(
          nullptr, x, BtB, xw, nullptr, nullptr, M, RB * 256);
    gather_kernel<<<(M + 3) / 4, 256, 0, stream>>>(offs, ev, xw, out, M, R, RB, b * RB);
  }

  relu_kernel<<<(n4 + 255) / 256, 256, 0, stream>>>(out, n4);
}

// Round 6
// 560.483 us; speedup vs baseline: 5.4387x; 1.2065x over previous
//
#include <hip/hip_runtime.h>
#include <hip/hip_bf16.h>
#include <stdint.h>

#define D 256

typedef __attribute__((ext_vector_type(8))) short bf16x8;
typedef __attribute__((ext_vector_type(4))) float f32x4;
typedef __attribute__((ext_vector_type(4))) unsigned int u32x4;

#define GLOBAL_AS __attribute__((address_space(1)))
#define LDS_AS __attribute__((address_space(3)))

__device__ __forceinline__ unsigned short f2bf(float f) {
  union { float f; unsigned int u; } c; c.f = f;
  unsigned int r = (c.u + 0x7fffu + ((c.u >> 16) & 1u)) >> 16;
  return (unsigned short)r;
}
__device__ __forceinline__ float bf2f(unsigned short h) {
  union { unsigned int u; float f; } c; c.u = ((unsigned int)h) << 16;
  return c.f;
}

// ---------------- prep: x fp32 -> bf16 ----------------
__global__ void convert_x_kernel(const float* __restrict__ x,
                                 unsigned short* __restrict__ xb, int n4) {
  int i = blockIdx.x * blockDim.x + threadIdx.x;
  if (i >= n4) return;
  float4 v = reinterpret_cast<const float4*>(x)[i];
  ushort4 o;
  o.x = f2bf(v.x); o.y = f2bf(v.y); o.z = f2bf(v.z); o.w = f2bf(v.w);
  reinterpret_cast<ushort4*>(xb)[i] = o;
}

// ---------------- prep: Wt[r][h][d] = W_r[d][h] (bf16), r==R -> W_self ----------------
__global__ void transpose_w_kernel(const float* __restrict__ Wrel,
                                   const float* __restrict__ Wself,
                                   unsigned short* __restrict__ Wt, int R) {
  __shared__ unsigned short tile[64][65];
  int r = blockIdx.z;
  const float* src = (r == R) ? Wself : (Wrel + (size_t)r * D * D);
  int d0 = blockIdx.x * 64, h0 = blockIdx.y * 64;
  for (int i = threadIdx.x; i < 64 * 64; i += blockDim.x) {
    int row = i >> 6, col = i & 63;  // row: d, col: h
    tile[row][col] = f2bf(src[(size_t)(d0 + row) * D + h0 + col]);
  }
  __syncthreads();
  for (int i = threadIdx.x; i < 64 * 64; i += blockDim.x) {
    int row = i >> 6, col = i & 63;  // row: h, col: d
    Wt[(size_t)r * D * D + (size_t)(h0 + row) * D + d0 + col] = tile[col][row];
  }
}

// ---------------- MFMA GEMM: C = A(M,256) @ Bt(n,256)^T ----------------
// XB=1: A is bf16 (global_load_lds staging). XB=0: A is fp32 (reg-stage + cvt).
// MODE 0: C -> Cbf (bf16), width ldc, LDS-staged epilogue
// MODE 1: C -> Cf (fp32) + bias, ldc = 256, direct stores
template <int MODE, int XB>
__global__ __launch_bounds__(256) void gemm_kernel(
    const unsigned short* __restrict__ Abf,
    const float* __restrict__ Af,
    const unsigned short* __restrict__ Bt,
    unsigned short* __restrict__ Cbf,
    float* __restrict__ Cf,
    const float* __restrict__ bias, int M, int ldc) {
  __shared__ unsigned short smem[128 * 128];  // 32KB; As=[0,8192), Bs=[8192,16384)
  unsigned short* As = smem;
  unsigned short* Bs = smem + 8192;

  const int tid = threadIdx.x;
  const int lane = tid & 63;
  const int wid = tid >> 6;
  const int wm = wid >> 1, wn = wid & 1;
  const int m0 = blockIdx.x * 128;
  const int n0 = blockIdx.y * 128;

  f32x4 acc[4][4] = {};

  for (int k0 = 0; k0 < 256; k0 += 64) {
    __syncthreads();  // previous iter's LDS reads done
    for (int i = 0; i < 4; ++i) {
      int chunk = i * 4 + wid;               // 0..15
      int row = chunk * 8 + (lane >> 3);     // 0..127
      int col = (lane & 7) * 8;              // 0..56
      const unsigned short* gb = Bt + (size_t)(n0 + row) * 256 + k0 + col;
      __builtin_amdgcn_global_load_lds((GLOBAL_AS void*)(void*)gb,
                                       (LDS_AS void*)(Bs + chunk * 512), 16, 0, 0);
    }
    if (XB) {
      for (int i = 0; i < 4; ++i) {
        int chunk = i * 4 + wid;
        int row = chunk * 8 + (lane >> 3);
        int col = (lane & 7) * 8;
        int ar = m0 + row; if (ar > M - 1) ar = M - 1;
        const unsigned short* ga = Abf + (size_t)ar * 256 + k0 + col;
        __builtin_amdgcn_global_load_lds((GLOBAL_AS void*)(void*)ga,
                                         (LDS_AS void*)(As + chunk * 512), 16, 0, 0);
      }
    } else {
      for (int i = 0; i < 8; ++i) {
        int idx = i * 256 + tid;     // 0..2047
        int row = idx >> 4;          // 0..127
        int c4 = idx & 15;           // 0..15 (x4 floats)
        int ar = m0 + row; if (ar > M - 1) ar = M - 1;
        float4 v = *reinterpret_cast<const float4*>(Af + (size_t)ar * 256 + k0 + c4 * 4);
        ushort4 o;
        o.x = f2bf(v.x); o.y = f2bf(v.y); o.z = f2bf(v.z); o.w = f2bf(v.w);
        *reinterpret_cast<ushort4*>(&As[row * 64 + c4 * 4]) = o;
      }
    }
    __syncthreads();  // drains vmcnt + lgkmcnt -> LDS ready
    for (int kk = 0; kk < 2; ++kk) {
      bf16x8 af[4], bfr[4];
      int kof = kk * 32 + (lane >> 4) * 8;
      for (int mi = 0; mi < 4; ++mi)
        af[mi] = *(const bf16x8*)&As[(wm * 64 + mi * 16 + (lane & 15)) * 64 + kof];
      for (int ni = 0; ni < 4; ++ni)
        bfr[ni] = *(const bf16x8*)&Bs[(wn * 64 + ni * 16 + (lane & 15)) * 64 + kof];
      for (int mi = 0; mi < 4; ++mi)
        for (int ni = 0; ni < 4; ++ni)
          acc[mi][ni] = __builtin_amdgcn_mfma_f32_16x16x32_bf16(
              af[mi], bfr[ni], acc[mi][ni], 0, 0, 0);
    }
  }

  if (MODE == 1) {
    for (int mi = 0; mi < 4; ++mi)
      for (int ni = 0; ni < 4; ++ni) {
        int col = n0 + wn * 64 + ni * 16 + (lane & 15);
        int rbase = m0 + wm * 64 + mi * 16 + (lane >> 4) * 4;
        float b = bias[col];
        for (int j = 0; j < 4; ++j) {
          int row = rbase + j;
          if (row < M) Cf[(size_t)row * 256 + col] = acc[mi][ni][j] + b;
        }
      }
  } else {
    __syncthreads();  // all LDS reads of K-loop done before overwrite
    for (int mi = 0; mi < 4; ++mi)
      for (int ni = 0; ni < 4; ++ni) {
        int colt = wn * 64 + ni * 16 + (lane & 15);
        int rbt = wm * 64 + mi * 16 + (lane >> 4) * 4;
        for (int j = 0; j < 4; ++j)
          smem[(rbt + j) * 128 + colt] = f2bf(acc[mi][ni][j]);
      }
    __syncthreads();
    for (int i = 0; i < 8; ++i) {
      int c = i * 256 + tid;        // 0..2047 chunks of 16B
      int row = c >> 4;             // 0..127
      int cole = (c & 15) * 8;      // 0..120
      int grow = m0 + row;
      if (grow < M)
        *(u32x4*)&Cbf[(size_t)grow * ldc + n0 + cole] =
            *(const u32x4*)&smem[row * 128 + cole];
    }
  }
}

// ================= per-(batch,dst) CSR build =================
// bins: b*M + dst, b = rel / RB.  ev stores src*RB + (rel - b*RB)  -> gather
// needs NO div/mod: xw element offset = ev[s] << 8.
__global__ void hist_kernel(const int* __restrict__ ei, const int* __restrict__ et,
                            int* __restrict__ counts, int E, int M, int R, int RB) {
  for (int i = blockIdx.x * blockDim.x + threadIdx.x; i < E;
       i += gridDim.x * blockDim.x) {
    int dst = min(max(ei[E + i], 0), M - 1);
    int rel = min(max(et[i], 0), R - 1);
    int b = rel / RB;
    atomicAdd(&counts[b * M + dst], 1);
  }
}

__global__ void scan1_kernel(const int* __restrict__ counts, int* __restrict__ bsum,
                             int NBINS) {
  __shared__ int red[256];
  int i = blockIdx.x * 256 + threadIdx.x;
  red[threadIdx.x] = (i < NBINS) ? counts[i] : 0;
  __syncthreads();
  for (int s = 128; s > 0; s >>= 1) {
    if (threadIdx.x < s) red[threadIdx.x] += red[threadIdx.x + s];
    __syncthreads();
  }
  if (threadIdx.x == 0) bsum[blockIdx.x] = red[0];
}

__global__ void scan2_kernel(int* __restrict__ bsum, int NB) {  // exclusive, NB<=1024
  __shared__ int sh[1024];
  int t = threadIdx.x;
  int v = (t < NB) ? bsum[t] : 0;
  sh[t] = v;
  __syncthreads();
  for (int off = 1; off < 1024; off <<= 1) {
    int u = (t >= off) ? sh[t - off] : 0;
    __syncthreads();
    sh[t] += u;
    __syncthreads();
  }
  if (t < NB) bsum[t] = sh[t] - v;
}

__global__ void scan3_kernel(const int* __restrict__ counts, const int* __restrict__ bsum,
                             int* __restrict__ offs, int NBINS) {
  __shared__ int sh[256];
  int b = blockIdx.x, t = threadIdx.x;
  int i = b * 256 + t;
  int v = (i < NBINS) ? counts[i] : 0;
  sh[t] = v;
  __syncthreads();
  for (int off = 1; off < 256; off <<= 1) {
    int u = (t >= off) ? sh[t - off] : 0;
    __syncthreads();
    sh[t] += u;
    __syncthreads();
  }
  int excl = sh[t] - v + bsum[b];
  if (i < NBINS) offs[i] = excl;
  if (i == NBINS - 1) offs[NBINS] = excl + v;
}

__global__ void fill_kernel(const int* __restrict__ ei, const int* __restrict__ et,
                            const int* __restrict__ offs, int* __restrict__ cursor,
                            int* __restrict__ ev, int E, int M, int R, int RB) {
  for (int i = blockIdx.x * blockDim.x + threadIdx.x; i < E;
       i += gridDim.x * blockDim.x) {
    int dst = min(max(ei[E + i], 0), M - 1);
    int src = min(max(ei[i], 0), M - 1);
    int rel = min(max(et[i], 0), R - 1);
    int b = rel / RB;
    int bin = b * M + dst;
    int p = atomicAdd(&cursor[bin], 1);
    ev[offs[bin] + p] = src * RB + (rel - b * RB);
  }
}

// ---------------- gather: out[n] += sum over batch-CSR edges of xw[ev[s]] ----------------
// one wave per destination node; no atomics; unroll-4 for MLP; optional fused relu.
template <int RELU>
__global__ void gather_kernel(const int* __restrict__ offs, const int* __restrict__ ev,
                              const unsigned short* __restrict__ xw,
                              float* __restrict__ out, int M, int base) {
  int w = blockIdx.x * (blockDim.x >> 6) + (threadIdx.x >> 6);
  int lane = threadIdx.x & 63;
  if (w >= M) return;
  int beg = offs[base + w], end = offs[base + w + 1];
  float a0 = 0, a1 = 0, a2 = 0, a3 = 0;
  int s = beg;
  for (; s + 3 < end; s += 4) {
    int v0 = ev[s], v1 = ev[s + 1], v2 = ev[s + 2], v3 = ev[s + 3];
    ushort4 t0 = *((const ushort4*)(xw + ((size_t)v0 << 8)) + lane);
    ushort4 t1 = *((const ushort4*)(xw + ((size_t)v1 << 8)) + lane);
    ushort4 t2 = *((const ushort4*)(xw + ((size_t)v2 << 8)) + lane);
    ushort4 t3 = *((const ushort4*)(xw + ((size_t)v3 << 8)) + lane);
    a0 += bf2f(t0.x) + bf2f(t1.x) + bf2f(t2.x) + bf2f(t3.x);
    a1 += bf2f(t0.y) + bf2f(t1.y) + bf2f(t2.y) + bf2f(t3.y);
    a2 += bf2f(t0.z) + bf2f(t1.z) + bf2f(t2.z) + bf2f(t3.z);
    a3 += bf2f(t0.w) + bf2f(t1.w) + bf2f(t2.w) + bf2f(t3.w);
  }
  for (; s < end; ++s) {
    int v = ev[s];
    ushort4 t = *((const ushort4*)(xw + ((size_t)v << 8)) + lane);
    a0 += bf2f(t.x); a1 += bf2f(t.y); a2 += bf2f(t.z); a3 += bf2f(t.w);
  }
  if (RELU || end > beg) {
    float4* o = (float4*)(out + (size_t)w * 256) + lane;
    float4 cur = *o;
    cur.x += a0; cur.y += a1; cur.z += a2; cur.w += a3;
    if (RELU) {
      cur.x = fmaxf(cur.x, 0.f); cur.y = fmaxf(cur.y, 0.f);
      cur.z = fmaxf(cur.z, 0.f); cur.w = fmaxf(cur.w, 0.f);
    }
    *o = cur;
  }
}

// ---------------- relu in place (fallback path only) ----------------
__global__ void relu_kernel(float* __restrict__ out, int n4) {
  int i = blockIdx.x * blockDim.x + threadIdx.x;
  if (i >= n4) return;
  float4 v = reinterpret_cast<float4*>(out)[i];
  v.x = fmaxf(v.x, 0.f); v.y = fmaxf(v.y, 0.f);
  v.z = fmaxf(v.z, 0.f); v.w = fmaxf(v.w, 0.f);
  reinterpret_cast<float4*>(out)[i] = v;
}

// ======== ws-free fallback tier (correctness only; used only if ws too small) ========
__global__ void fb_self_kernel(const float* __restrict__ x,
                               const float* __restrict__ Wself,
                               const float* __restrict__ bias,
                               float* __restrict__ out, int M) {
  int w = blockIdx.x * (blockDim.x >> 6) + (threadIdx.x >> 6);
  int lane = threadIdx.x & 63;
  int nw = gridDim.x * (blockDim.x >> 6);
  for (int n = w; n < M; n += nw) {
    float a0 = 0, a1 = 0, a2 = 0, a3 = 0;
    const float* xr = x + (size_t)n * 256;
    for (int d = 0; d < 256; ++d) {
      float xv = xr[d];
      float4 wv = *reinterpret_cast<const float4*>(Wself + (size_t)d * 256 + lane * 4);
      a0 = fmaf(xv, wv.x, a0); a1 = fmaf(xv, wv.y, a1);
      a2 = fmaf(xv, wv.z, a2); a3 = fmaf(xv, wv.w, a3);
    }
    float4 b = *reinterpret_cast<const float4*>(bias + lane * 4);
    float4 o = {a0 + b.x, a1 + b.y, a2 + b.z, a3 + b.w};
    *reinterpret_cast<float4*>(out + (size_t)n * 256 + lane * 4) = o;
  }
}

__global__ void fb_edge_kernel(const int* __restrict__ ei, const int* __restrict__ et,
                               const float* __restrict__ x,
                               const float* __restrict__ Wrel,
                               float* __restrict__ out, int E, int M, int R) {
  int w = blockIdx.x * (blockDim.x >> 6) + (threadIdx.x >> 6);
  int lane = threadIdx.x & 63;
  int nw = gridDim.x * (blockDim.x >> 6);
  for (int e = w; e < E; e += nw) {
    int src = min(max(ei[e], 0), M - 1);
    int dst = min(max(ei[E + e], 0), M - 1);
    int rel = min(max(et[e], 0), R - 1);
    const float* xr = x + (size_t)src * 256;
    const float* W = Wrel + (size_t)rel * 256 * 256;
    float a0 = 0, a1 = 0, a2 = 0, a3 = 0;
    for (int d = 0; d < 256; ++d) {
      float xv = xr[d];
      float4 wv = *reinterpret_cast<const float4*>(W + (size_t)d * 256 + lane * 4);
      a0 = fmaf(xv, wv.x, a0); a1 = fmaf(xv, wv.y, a1);
      a2 = fmaf(xv, wv.z, a2); a3 = fmaf(xv, wv.w, a3);
    }
    float* o = out + (size_t)dst * 256 + lane * 4;
    atomicAdd(o + 0, a0);
    atomicAdd(o + 1, a1);
    atomicAdd(o + 2, a2);
    atomicAdd(o + 3, a3);
  }
}

extern "C" void kernel_launch(void* const* d_in, const int* in_sizes, int n_in,
                              void* d_out, int out_size, void* d_ws, size_t ws_size,
                              hipStream_t stream) {
  const float* x = (const float*)d_in[0];
  const int* ei = (const int*)d_in[1];
  const int* et = (const int*)d_in[2];
  const float* Wrel = (const float*)d_in[3];
  const float* Wself = (const float*)d_in[4];
  const float* bias = (const float*)d_in[5];
  float* out = (float*)d_out;

  const int M = in_sizes[0] / D;        // nodes
  const int E = in_sizes[1] / 2;        // edges
  const int R = in_sizes[3] / (D * D);  // relations

  const int MB = (M + 127) / 128;
  const int n4 = M * D / 4;

  // ---- ws plan: ints [counts nbM | cursor nbM | offs nbM+1 | bsum NB2 | ev E]
  //      then bf16 [Wt | xb? | xw(M*RB*D)]. Chosen from ws_size only (graph-safe).
  const size_t wtElems = (size_t)(R + 1) * D * D;
  const size_t xbElems = (size_t)M * D;
  const size_t yElems = (size_t)M * D;  // per relation

  int use_xb = 0, RB = 0, nb = 0;
  size_t nbM = 0, NB2 = 0;
  for (int pass = 0; pass < 2 && RB == 0; ++pass) {
    for (int rb = R; rb >= 1; rb >>= 1) {
      int nbc = (R + rb - 1) / rb;
      size_t nbm = (size_t)nbc * M;
      size_t nb2 = (nbm + 255) / 256;
      if (nb2 > 1024) continue;  // scan2 capacity
      size_t ib = (3 * nbm + 1 + nb2 + (size_t)E) * 4;
      if (ws_size < ib + 512) continue;
      size_t bfA = (ws_size - ib - 512) / 2;
      size_t need = wtElems + (pass == 0 ? xbElems : 0) + 512 + yElems * (size_t)rb;
      if (need <= bfA) {
        use_xb = (pass == 0); RB = rb; nb = nbc; nbM = nbm; NB2 = nb2;
        break;
      }
    }
  }

  if (RB == 0) {
    // ---- ws-free fallback: correct for ANY ws_size (never touches d_ws) ----
    fb_self_kernel<<<2048, 256, 0, stream>>>(x, Wself, bias, out, M);
    fb_edge_kernel<<<2048, 256, 0, stream>>>(ei, et, x, Wrel, out, E, M, R);
    relu_kernel<<<(n4 + 255) / 256, 256, 0, stream>>>(out, n4);
    return;
  }

  int* counts = (int*)d_ws;                 // nbM
  int* cursor = counts + nbM;               // nbM
  int* offs = cursor + nbM;                 // nbM+1
  int* bsum = offs + nbM + 1;               // NB2
  int* ev = bsum + NB2;                     // E
  uintptr_t bfp = (uintptr_t)(ev + E);
  bfp = (bfp + 255) & ~(uintptr_t)255;
  unsigned short* Wt = (unsigned short*)bfp;
  unsigned short* xb = Wt + wtElems;
  size_t off = wtElems + (use_xb ? xbElems : 0);
  off = (off + 255) & ~(size_t)255;
  unsigned short* xw = Wt + off;

  // ---- CSR build (per batch,dst bins) ----
  hipMemsetAsync(counts, 0, 2 * nbM * 4, stream);  // counts + cursor
  hist_kernel<<<1024, 256, 0, stream>>>(ei, et, counts, E, M, R, RB);
  scan1_kernel<<<(int)NB2, 256, 0, stream>>>(counts, bsum, (int)nbM);
  scan2_kernel<<<1, 1024, 0, stream>>>(bsum, (int)NB2);
  scan3_kernel<<<(int)NB2, 256, 0, stream>>>(counts, bsum, offs, (int)nbM);
  fill_kernel<<<1024, 256, 0, stream>>>(ei, et, offs, cursor, ev, E, M, R, RB);

  // ---- dense path ----
  transpose_w_kernel<<<dim3(4, 4, R + 1), 256, 0, stream>>>(Wrel, Wself, Wt, R);
  if (use_xb)
    convert_x_kernel<<<(n4 + 255) / 256, 256, 0, stream>>>(x, xb, n4);

  if (use_xb)
    gemm_kernel<1, 1><<<dim3(MB, 2), 256, 0, stream>>>(
        xb, nullptr, Wt + (size_t)R * D * D, nullptr, out, bias, M, 256);
  else
    gemm_kernel<1, 0><<<dim3(MB, 2), 256, 0, stream>>>(
        nullptr, x, Wt + (size_t)R * D * D, nullptr, out, bias, M, 256);

  for (int b = 0; b < nb; ++b) {
    int rlo = b * RB;
    int rbw = min(RB, R - rlo);  // last batch width (R power-of-2 -> == RB)
    const unsigned short* BtB = Wt + (size_t)rlo * D * D;
    if (use_xb)
      gemm_kernel<0, 1><<<dim3(MB, rbw * 2), 256, 0, stream>>>(
          xb, nullptr, BtB, xw, nullptr, nullptr, M, rbw * 256);
    else
      gemm_kernel<0, 0><<<dim3(MB, rbw * 2), 256, 0, stream>>>(
          nullptr, x, BtB, xw, nullptr, nullptr, M, rbw * 256);
    if (b == nb - 1)
      gather_kernel<1><<<(M + 3) / 4, 256, 0, stream>>>(offs, ev, xw, out, M, b * M);
    else
      gather_kernel<0><<<(M + 3) / 4, 256, 0, stream>>>(offs, ev, xw, out, M, b * M);
  }
}

// Round 8
// 517.563 us; speedup vs baseline: 5.8897x; 1.0829x over previous
//
#include <hip/hip_runtime.h>
#include <hip/hip_bf16.h>
#include <stdint.h>

#define D 256

typedef __attribute__((ext_vector_type(8))) short bf16x8;
typedef __attribute__((ext_vector_type(4))) float f32x4;
typedef __attribute__((ext_vector_type(4))) unsigned int u32x4;

#define GLOBAL_AS __attribute__((address_space(1)))
#define LDS_AS __attribute__((address_space(3)))

__device__ __forceinline__ unsigned short f2bf(float f) {
  union { float f; unsigned int u; } c; c.f = f;
  unsigned int r = (c.u + 0x7fffu + ((c.u >> 16) & 1u)) >> 16;
  return (unsigned short)r;
}
__device__ __forceinline__ float bf2f(unsigned short h) {
  union { unsigned int u; float f; } c; c.u = ((unsigned int)h) << 16;
  return c.f;
}

// ---------------- prep: x fp32 -> bf16 ----------------
__global__ void convert_x_kernel(const float* __restrict__ x,
                                 unsigned short* __restrict__ xb, int n4) {
  int i = blockIdx.x * blockDim.x + threadIdx.x;
  if (i >= n4) return;
  float4 v = reinterpret_cast<const float4*>(x)[i];
  ushort4 o;
  o.x = f2bf(v.x); o.y = f2bf(v.y); o.z = f2bf(v.z); o.w = f2bf(v.w);
  reinterpret_cast<ushort4*>(xb)[i] = o;
}

// ---------------- prep: Wt[r][h][d] = W_r[d][h] (bf16), r==R -> W_self ----------------
__global__ void transpose_w_kernel(const float* __restrict__ Wrel,
                                   const float* __restrict__ Wself,
                                   unsigned short* __restrict__ Wt, int R) {
  __shared__ unsigned short tile[64][65];
  int r = blockIdx.z;
  const float* src = (r == R) ? Wself : (Wrel + (size_t)r * D * D);
  int d0 = blockIdx.x * 64, h0 = blockIdx.y * 64;
  for (int i = threadIdx.x; i < 64 * 64; i += blockDim.x) {
    int row = i >> 6, col = i & 63;  // row: d, col: h
    tile[row][col] = f2bf(src[(size_t)(d0 + row) * D + h0 + col]);
  }
  __syncthreads();
  for (int i = threadIdx.x; i < 64 * 64; i += blockDim.x) {
    int row = i >> 6, col = i & 63;  // row: h, col: d
    Wt[(size_t)r * D * D + (size_t)(h0 + row) * D + d0 + col] = tile[col][row];
  }
}

// ---------------- MFMA GEMM: C = A(M,256) @ Bt(n,256)^T ----------------
// 1-D grid, panel-swizzled: PANEL=8 m-tiles per panel, m fastest within panel.
// Consecutive blocks round-robin the 8 XCDs -> each XCD pins one A-tile in its
// L2 and sweeps n-tiles (A fetched ~once from HBM instead of once per n-tile).
// XB=1: A is bf16 (global_load_lds staging). XB=0: A is fp32 (reg-stage + cvt).
// MODE 0: C -> Cbf (bf16), width ldc, LDS-staged epilogue
// MODE 1: C -> Cf (fp32) + bias, ldc = 256, direct stores
template <int MODE, int XB>
__global__ __launch_bounds__(256) void gemm_kernel(
    const unsigned short* __restrict__ Abf,
    const float* __restrict__ Af,
    const unsigned short* __restrict__ Bt,
    unsigned short* __restrict__ Cbf,
    float* __restrict__ Cf,
    const float* __restrict__ bias, int M, int ldc, int ntiles) {
  __shared__ unsigned short smem[128 * 128];  // 32KB; As=[0,8192), Bs=[8192,16384)
  unsigned short* As = smem;
  unsigned short* Bs = smem + 8192;

  const int tid = threadIdx.x;
  const int lane = tid & 63;
  const int wid = tid >> 6;
  const int wm = wid >> 1, wn = wid & 1;

  // panel-swizzle decode
  const int MBt = (M + 127) >> 7;
  const int PANEL = 8;
  const int per_panel = PANEL * ntiles;
  const int panel = blockIdx.x / per_panel;
  const int rem = blockIdx.x - panel * per_panel;
  const int pm0 = panel * PANEL;
  const int ph = min(PANEL, MBt - pm0);
  const int mi = pm0 + rem % ph;
  const int ni = rem / ph;
  const int m0 = mi * 128;
  const int n0 = ni * 128;

  f32x4 acc[4][4] = {};

  for (int k0 = 0; k0 < 256; k0 += 64) {
    __syncthreads();  // previous iter's LDS reads done
    for (int i = 0; i < 4; ++i) {
      int chunk = i * 4 + wid;               // 0..15
      int row = chunk * 8 + (lane >> 3);     // 0..127
      int col = (lane & 7) * 8;              // 0..56
      const unsigned short* gb = Bt + (size_t)(n0 + row) * 256 + k0 + col;
      __builtin_amdgcn_global_load_lds((GLOBAL_AS void*)(void*)gb,
                                       (LDS_AS void*)(Bs + chunk * 512), 16, 0, 0);
    }
    if (XB) {
      for (int i = 0; i < 4; ++i) {
        int chunk = i * 4 + wid;
        int row = chunk * 8 + (lane >> 3);
        int col = (lane & 7) * 8;
        int ar = m0 + row; if (ar > M - 1) ar = M - 1;
        const unsigned short* ga = Abf + (size_t)ar * 256 + k0 + col;
        __builtin_amdgcn_global_load_lds((GLOBAL_AS void*)(void*)ga,
                                         (LDS_AS void*)(As + chunk * 512), 16, 0, 0);
      }
    } else {
      for (int i = 0; i < 8; ++i) {
        int idx = i * 256 + tid;     // 0..2047
        int row = idx >> 4;          // 0..127
        int c4 = idx & 15;           // 0..15 (x4 floats)
        int ar = m0 + row; if (ar > M - 1) ar = M - 1;
        float4 v = *reinterpret_cast<const float4*>(Af + (size_t)ar * 256 + k0 + c4 * 4);
        ushort4 o;
        o.x = f2bf(v.x); o.y = f2bf(v.y); o.z = f2bf(v.z); o.w = f2bf(v.w);
        *reinterpret_cast<ushort4*>(&As[row * 64 + c4 * 4]) = o;
      }
    }
    __syncthreads();  // drains vmcnt + lgkmcnt -> LDS ready
    for (int kk = 0; kk < 2; ++kk) {
      bf16x8 af[4], bfr[4];
      int kof = kk * 32 + (lane >> 4) * 8;
      for (int mi2 = 0; mi2 < 4; ++mi2)
        af[mi2] = *(const bf16x8*)&As[(wm * 64 + mi2 * 16 + (lane & 15)) * 64 + kof];
      for (int ni2 = 0; ni2 < 4; ++ni2)
        bfr[ni2] = *(const bf16x8*)&Bs[(wn * 64 + ni2 * 16 + (lane & 15)) * 64 + kof];
      for (int mi2 = 0; mi2 < 4; ++mi2)
        for (int ni2 = 0; ni2 < 4; ++ni2)
          acc[mi2][ni2] = __builtin_amdgcn_mfma_f32_16x16x32_bf16(
              af[mi2], bfr[ni2], acc[mi2][ni2], 0, 0, 0);
    }
  }

  if (MODE == 1) {
    for (int mi2 = 0; mi2 < 4; ++mi2)
      for (int ni2 = 0; ni2 < 4; ++ni2) {
        int col = n0 + wn * 64 + ni2 * 16 + (lane & 15);
        int rbase = m0 + wm * 64 + mi2 * 16 + (lane >> 4) * 4;
        float b = bias[col];
        for (int j = 0; j < 4; ++j) {
          int row = rbase + j;
          if (row < M) Cf[(size_t)row * 256 + col] = acc[mi2][ni2][j] + b;
        }
      }
  } else {
    __syncthreads();  // all LDS reads of K-loop done before overwrite
    for (int mi2 = 0; mi2 < 4; ++mi2)
      for (int ni2 = 0; ni2 < 4; ++ni2) {
        int colt = wn * 64 + ni2 * 16 + (lane & 15);
        int rbt = wm * 64 + mi2 * 16 + (lane >> 4) * 4;
        for (int j = 0; j < 4; ++j)
          smem[(rbt + j) * 128 + colt] = f2bf(acc[mi2][ni2][j]);
      }
    __syncthreads();
    for (int i = 0; i < 8; ++i) {
      int c = i * 256 + tid;        // 0..2047 chunks of 16B
      int row = c >> 4;             // 0..127
      int cole = (c & 15) * 8;      // 0..120
      int grow = m0 + row;
      if (grow < M)
        *(u32x4*)&Cbf[(size_t)grow * ldc + n0 + cole] =
            *(const u32x4*)&smem[row * 128 + cole];
    }
  }
}

// ================= per-(batch,dst) CSR build =================
// bins: b*M + dst, b = rel / RB.  ev stores src*RB + (rel - b*RB)  -> gather
// needs NO div/mod: xw element offset = ev[s] << 8.
__global__ void hist_kernel(const int* __restrict__ ei, const int* __restrict__ et,
                            int* __restrict__ counts, int E, int M, int R, int RB) {
  for (int i = blockIdx.x * blockDim.x + threadIdx.x; i < E;
       i += gridDim.x * blockDim.x) {
    int dst = min(max(ei[E + i], 0), M - 1);
    int rel = min(max(et[i], 0), R - 1);
    int b = rel / RB;
    atomicAdd(&counts[b * M + dst], 1);
  }
}

__global__ void scan1_kernel(const int* __restrict__ counts, int* __restrict__ bsum,
                             int NBINS) {
  __shared__ int red[256];
  int i = blockIdx.x * 256 + threadIdx.x;
  red[threadIdx.x] = (i < NBINS) ? counts[i] : 0;
  __syncthreads();
  for (int s = 128; s > 0; s >>= 1) {
    if (threadIdx.x < s) red[threadIdx.x] += red[threadIdx.x + s];
    __syncthreads();
  }
  if (threadIdx.x == 0) bsum[blockIdx.x] = red[0];
}

__global__ void scan2_kernel(int* __restrict__ bsum, int NB) {  // exclusive, NB<=1024
  __shared__ int sh[1024];
  int t = threadIdx.x;
  int v = (t < NB) ? bsum[t] : 0;
  sh[t] = v;
  __syncthreads();
  for (int off = 1; off < 1024; off <<= 1) {
    int u = (t >= off) ? sh[t - off] : 0;
    __syncthreads();
    sh[t] += u;
    __syncthreads();
  }
  if (t < NB) bsum[t] = sh[t] - v;
}

__global__ void scan3_kernel(const int* __restrict__ counts, const int* __restrict__ bsum,
                             int* __restrict__ offs, int NBINS) {
  __shared__ int sh[256];
  int b = blockIdx.x, t = threadIdx.x;
  int i = b * 256 + t;
  int v = (i < NBINS) ? counts[i] : 0;
  sh[t] = v;
  __syncthreads();
  for (int off = 1; off < 256; off <<= 1) {
    int u = (t >= off) ? sh[t - off] : 0;
    __syncthreads();
    sh[t] += u;
    __syncthreads();
  }
  int excl = sh[t] - v + bsum[b];
  if (i < NBINS) offs[i] = excl;
  if (i == NBINS - 1) offs[NBINS] = excl + v;
}

__global__ void fill_kernel(const int* __restrict__ ei, const int* __restrict__ et,
                            const int* __restrict__ offs, int* __restrict__ cursor,
                            int* __restrict__ ev, int E, int M, int R, int RB) {
  for (int i = blockIdx.x * blockDim.x + threadIdx.x; i < E;
       i += gridDim.x * blockDim.x) {
    int dst = min(max(ei[E + i], 0), M - 1);
    int src = min(max(ei[i], 0), M - 1);
    int rel = min(max(et[i], 0), R - 1);
    int b = rel / RB;
    int bin = b * M + dst;
    int p = atomicAdd(&cursor[bin], 1);
    ev[offs[bin] + p] = src * RB + (rel - b * RB);
  }
}

// ---------------- gather: out[n] += sum over batch-CSR edges of xw[ev[s]] ----------------
// one wave per destination node; no atomics; unroll-4 for MLP; optional fused relu.
template <int RELU>
__global__ void gather_kernel(const int* __restrict__ offs, const int* __restrict__ ev,
                              const unsigned short* __restrict__ xw,
                              float* __restrict__ out, int M, int base) {
  int w = blockIdx.x * (blockDim.x >> 6) + (threadIdx.x >> 6);
  int lane = threadIdx.x & 63;
  if (w >= M) return;
  int beg = offs[base + w], end = offs[base + w + 1];
  float a0 = 0, a1 = 0, a2 = 0, a3 = 0;
  int s = beg;
  for (; s + 3 < end; s += 4) {
    int v0 = ev[s], v1 = ev[s + 1], v2 = ev[s + 2], v3 = ev[s + 3];
    ushort4 t0 = *((const ushort4*)(xw + ((size_t)v0 << 8)) + lane);
    ushort4 t1 = *((const ushort4*)(xw + ((size_t)v1 << 8)) + lane);
    ushort4 t2 = *((const ushort4*)(xw + ((size_t)v2 << 8)) + lane);
    ushort4 t3 = *((const ushort4*)(xw + ((size_t)v3 << 8)) + lane);
    a0 += bf2f(t0.x) + bf2f(t1.x) + bf2f(t2.x) + bf2f(t3.x);
    a1 += bf2f(t0.y) + bf2f(t1.y) + bf2f(t2.y) + bf2f(t3.y);
    a2 += bf2f(t0.z) + bf2f(t1.z) + bf2f(t2.z) + bf2f(t3.z);
    a3 += bf2f(t0.w) + bf2f(t1.w) + bf2f(t2.w) + bf2f(t3.w);
  }
  for (; s < end; ++s) {
    int v = ev[s];
    ushort4 t = *((const ushort4*)(xw + ((size_t)v << 8)) + lane);
    a0 += bf2f(t.x); a1 += bf2f(t.y); a2 += bf2f(t.z); a3 += bf2f(t.w);
  }
  if (RELU || end > beg) {
    float4* o = (float4*)(out + (size_t)w * 256) + lane;
    float4 cur = *o;
    cur.x += a0; cur.y += a1; cur.z += a2; cur.w += a3;
    if (RELU) {
      cur.x = fmaxf(cur.x, 0.f); cur.y = fmaxf(cur.y, 0.f);
      cur.z = fmaxf(cur.z, 0.f); cur.w = fmaxf(cur.w, 0.f);
    }
    *o = cur;
  }
}

// ---------------- relu in place (fallback path only) ----------------
__global__ void relu_kernel(float* __restrict__ out, int n4) {
  int i = blockIdx.x * blockDim.x + threadIdx.x;
  if (i >= n4) return;
  float4 v = reinterpret_cast<float4*>(out)[i];
  v.x = fmaxf(v.x, 0.f); v.y = fmaxf(v.y, 0.f);
  v.z = fmaxf(v.z, 0.f); v.w = fmaxf(v.w, 0.f);
  reinterpret_cast<float4*>(out)[i] = v;
}

// ======== ws-free fallback tier (correctness only; used only if ws too small) ========
__global__ void fb_self_kernel(const float* __restrict__ x,
                               const float* __restrict__ Wself,
                               const float* __restrict__ bias,
                               float* __restrict__ out, int M) {
  int w = blockIdx.x * (blockDim.x >> 6) + (threadIdx.x >> 6);
  int lane = threadIdx.x & 63;
  int nw = gridDim.x * (blockDim.x >> 6);
  for (int n = w; n < M; n += nw) {
    float a0 = 0, a1 = 0, a2 = 0, a3 = 0;
    const float* xr = x + (size_t)n * 256;
    for (int d = 0; d < 256; ++d) {
      float xv = xr[d];
      float4 wv = *reinterpret_cast<const float4*>(Wself + (size_t)d * 256 + lane * 4);
      a0 = fmaf(xv, wv.x, a0); a1 = fmaf(xv, wv.y, a1);
      a2 = fmaf(xv, wv.z, a2); a3 = fmaf(xv, wv.w, a3);
    }
    float4 b = *reinterpret_cast<const float4*>(bias + lane * 4);
    float4 o = {a0 + b.x, a1 + b.y, a2 + b.z, a3 + b.w};
    *reinterpret_cast<float4*>(out + (size_t)n * 256 + lane * 4) = o;
  }
}

__global__ void fb_edge_kernel(const int* __restrict__ ei, const int* __restrict__ et,
                               const float* __restrict__ x,
                               const float* __restrict__ Wrel,
                               float* __restrict__ out, int E, int M, int R) {
  int w = blockIdx.x * (blockDim.x >> 6) + (threadIdx.x >> 6);
  int lane = threadIdx.x & 63;
  int nw = gridDim.x * (blockDim.x >> 6);
  for (int e = w; e < E; e += nw) {
    int src = min(max(ei[e], 0), M - 1);
    int dst = min(max(ei[E + e], 0), M - 1);
    int rel = min(max(et[e], 0), R - 1);
    const float* xr = x + (size_t)src * 256;
    const float* W = Wrel + (size_t)rel * 256 * 256;
    float a0 = 0, a1 = 0, a2 = 0, a3 = 0;
    for (int d = 0; d < 256; ++d) {
      float xv = xr[d];
      float4 wv = *reinterpret_cast<const float4*>(W + (size_t)d * 256 + lane * 4);
      a0 = fmaf(xv, wv.x, a0); a1 = fmaf(xv, wv.y, a1);
      a2 = fmaf(xv, wv.z, a2); a3 = fmaf(xv, wv.w, a3);
    }
    float* o = out + (size_t)dst * 256 + lane * 4;
    atomicAdd(o + 0, a0);
    atomicAdd(o + 1, a1);
    atomicAdd(o + 2, a2);
    atomicAdd(o + 3, a3);
  }
}

extern "C" void kernel_launch(void* const* d_in, const int* in_sizes, int n_in,
                              void* d_out, int out_size, void* d_ws, size_t ws_size,
                              hipStream_t stream) {
  const float* x = (const float*)d_in[0];
  const int* ei = (const int*)d_in[1];
  const int* et = (const int*)d_in[2];
  const float* Wrel = (const float*)d_in[3];
  const float* Wself = (const float*)d_in[4];
  const float* bias = (const float*)d_in[5];
  float* out = (float*)d_out;

  const int M = in_sizes[0] / D;        // nodes
  const int E = in_sizes[1] / 2;        // edges
  const int R = in_sizes[3] / (D * D);  // relations

  const int MB = (M + 127) / 128;
  const int n4 = M * D / 4;

  // ---- ws plan: ints [counts nbM | cursor nbM | offs nbM+1 | bsum NB2 | ev E]
  //      then bf16 [Wt | xb? | xw(M*RB*D)]. Chosen from ws_size only (graph-safe).
  const size_t wtElems = (size_t)(R + 1) * D * D;
  const size_t xbElems = (size_t)M * D;
  const size_t yElems = (size_t)M * D;  // per relation

  int use_xb = 0, RB = 0, nb = 0;
  size_t nbM = 0, NB2 = 0;
  for (int pass = 0; pass < 2 && RB == 0; ++pass) {
    for (int rb = R; rb >= 1; rb >>= 1) {
      int nbc = (R + rb - 1) / rb;
      size_t nbm = (size_t)nbc * M;
      size_t nb2 = (nbm + 255) / 256;
      if (nb2 > 1024) continue;  // scan2 capacity
      size_t ib = (3 * nbm + 1 + nb2 + (size_t)E) * 4;
      if (ws_size < ib + 512) continue;
      size_t bfA = (ws_size - ib - 512) / 2;
      size_t need = wtElems + (pass == 0 ? xbElems : 0) + 512 + yElems * (size_t)rb;
      if (need <= bfA) {
        use_xb = (pass == 0); RB = rb; nb = nbc; nbM = nbm; NB2 = nb2;
        break;
      }
    }
  }

  if (RB == 0) {
    // ---- ws-free fallback: correct for ANY ws_size (never touches d_ws) ----
    fb_self_kernel<<<2048, 256, 0, stream>>>(x, Wself, bias, out, M);
    fb_edge_kernel<<<2048, 256, 0, stream>>>(ei, et, x, Wrel, out, E, M, R);
    relu_kernel<<<(n4 + 255) / 256, 256, 0, stream>>>(out, n4);
    return;
  }

  int* counts = (int*)d_ws;                 // nbM
  int* cursor = counts + nbM;               // nbM
  int* offs = cursor + nbM;                 // nbM+1
  int* bsum = offs + nbM + 1;               // NB2
  int* ev = bsum + NB2;                     // E
  uintptr_t bfp = (uintptr_t)(ev + E);
  bfp = (bfp + 255) & ~(uintptr_t)255;
  unsigned short* Wt = (unsigned short*)bfp;
  unsigned short* xb = Wt + wtElems;
  size_t off = wtElems + (use_xb ? xbElems : 0);
  off = (off + 255) & ~(size_t)255;
  unsigned short* xw = Wt + off;

  // ---- CSR build (per batch,dst bins) ----
  hipMemsetAsync(counts, 0, 2 * nbM * 4, stream);  // counts + cursor
  hist_kernel<<<1024, 256, 0, stream>>>(ei, et, counts, E, M, R, RB);
  scan1_kernel<<<(int)NB2, 256, 0, stream>>>(counts, bsum, (int)nbM);
  scan2_kernel<<<1, 1024, 0, stream>>>(bsum, (int)NB2);
  scan3_kernel<<<(int)NB2, 256, 0, stream>>>(counts, bsum, offs, (int)nbM);
  fill_kernel<<<1024, 256, 0, stream>>>(ei, et, offs, cursor, ev, E, M, R, RB);

  // ---- dense path ----
  transpose_w_kernel<<<dim3(4, 4, R + 1), 256, 0, stream>>>(Wrel, Wself, Wt, R);
  if (use_xb)
    convert_x_kernel<<<(n4 + 255) / 256, 256, 0, stream>>>(x, xb, n4);

  if (use_xb)
    gemm_kernel<1, 1><<<MB * 2, 256, 0, stream>>>(
        xb, nullptr, Wt + (size_t)R * D * D, nullptr, out, bias, M, 256, 2);
  else
    gemm_kernel<1, 0><<<MB * 2, 256, 0, stream>>>(
        nullptr, x, Wt + (size_t)R * D * D, nullptr, out, bias, M, 256, 2);

  for (int b = 0; b < nb; ++b) {
    int rlo = b * RB;
    int rbw = min(RB, R - rlo);  // last batch width (R power-of-2 -> == RB)
    const unsigned short* BtB = Wt + (size_t)rlo * D * D;
    if (use_xb)
      gemm_kernel<0, 1><<<MB * rbw * 2, 256, 0, stream>>>(
          xb, nullptr, BtB, xw, nullptr, nullptr, M, rbw * 256, rbw * 2);
    else
      gemm_kernel<0, 0><<<MB * rbw * 2, 256, 0, stream>>>(
          nullptr, x, BtB, xw, nullptr, nullptr, M, rbw * 256, rbw * 2);
    if (b == nb - 1)
      gather_kernel<1><<<(M + 3) / 4, 256, 0, stream>>>(offs, ev, xw, out, M, b * M);
    else
      gather_kernel<0><<<(M + 3) / 4, 256, 0, stream>>>(offs, ev, xw, out, M, b * M);
  }
}